// Round 3
// baseline (1261.960 us; speedup 1.0000x reference)
//
#include <hip/hip_runtime.h>
#include <hip/hip_bf16.h>

#define HID 50
#define FOURH 200
#define TSTEPS 2048
#define NBATCH 1024

typedef float v2f __attribute__((ext_vector_type(2)));
typedef float v4f __attribute__((ext_vector_type(4)));

__device__ __forceinline__ float fast_sigmoid(float x) {
    // 1/(1+e^-x); safe at both tails
    return 1.0f / (1.0f + __expf(-x));
}
__device__ __forceinline__ float fast_tanh(float x) {
    // saturating, NaN-free
    return 1.0f - 2.0f / (__expf(2.0f * x) + 1.0f);
}

// Two waves per batch element (2048 waves = 2 waves/SIMD for latency hiding).
// Wave 0 owns gate columns {i, g}; wave 1 owns {f, o}. Each lane l owns hidden
// unit min(l,49) for its wave's two gates: 50 k-MACs x 2 gates = 25 v_pk_fma
// pairs x 2, with 4 independent accumulator chains. Wave 1 activates {f,o} and
// ships them via LDS; wave 0 keeps the c state, does the c/h update, and
// publishes h (13 x ds_read_b128 broadcast next step). 2 barriers/step.
__global__ __launch_bounds__(128, 2)
void lstm_2wave_kernel(const float* __restrict__ x,
                       const float* __restrict__ Wx,
                       const float* __restrict__ Wh,
                       const float* __restrict__ bias,
                       const float* __restrict__ Wd,
                       const float* __restrict__ bd,
                       float* __restrict__ out) {
    const int b    = blockIdx.x;
    const int tid  = threadIdx.x;
    const int wave = tid >> 6;               // 0: {i,g}   1: {f,o}
    const int lane = tid & 63;
    const int lc   = (lane < HID) ? lane : (HID - 1);

    __shared__ __align__(16) float xs[TSTEPS];   // 8 KB input sequence
    __shared__ __align__(16) float hbuf[52];     // h, padded to 13 float4
    __shared__ __align__(16) v2f   gbuf[64];     // wave1 -> wave0: {f_act, o_act}

    // Stage x (coalesced float4).
    const float4* xb4 = (const float4*)(x + (size_t)b * TSTEPS);
    float4* xs4 = (float4*)xs;
    for (int i = tid; i < TSTEPS / 4; i += 128) xs4[i] = xb4[i];

    // Gate columns for this wave (gate order i,f,g,o).
    const int col_a = wave ? (HID + lc)     : lc;             // f : i
    const int col_b = wave ? (3 * HID + lc) : (2 * HID + lc); // o : g

    // Weights paired along k for v_pk_fma_f32. 26 pairs cover k=0..51
    // (k=50,51 are zero padding, matching hbuf's zero pad).
    v2f wa[26], wb[26];
    #pragma unroll
    for (int k2 = 0; k2 < 25; ++k2) {
        const float* r0 = Wh + (2 * k2) * FOURH;
        const float* r1 = Wh + (2 * k2 + 1) * FOURH;
        wa[k2] = v2f{r0[col_a], r1[col_a]};
        wb[k2] = v2f{r0[col_b], r1[col_b]};
    }
    wa[25] = v2f{0.0f, 0.0f};
    wb[25] = v2f{0.0f, 0.0f};
    const float wx_a = Wx[col_a], bi_a = bias[col_a];
    const float wx_b = Wx[col_b], bi_b = bias[col_b];

    // Branchless per-wave activation for gate b: wave0 needs tanh, wave1 sigmoid.
    // tanh(z) = 2*sigmoid(2z) - 1  -> act_b = scl_o * sigmoid(scl_i * z) + off.
    const float scl_i = wave ? 1.0f : 2.0f;
    const float scl_o = wave ? 1.0f : 2.0f;
    const float off_o = wave ? 0.0f : -1.0f;

    if (tid < 52) hbuf[tid] = 0.0f;
    float c = 0.0f;
    float h = 0.0f;
    __syncthreads();

    const v4f* h4p = (const v4f*)hbuf;

    for (int t = 0; t < TSTEPS; ++t) {
        const float xt = xs[t];
        // 4 independent pk-fma chains (2 per gate) for FMA-latency ILP.
        v2f a0 = {0.0f, 0.0f}, a1 = {0.0f, 0.0f};
        v2f b0 = {0.0f, 0.0f}, b1 = {0.0f, 0.0f};
        #pragma unroll
        for (int k4 = 0; k4 < 13; ++k4) {
            const v4f h4 = h4p[k4];                  // broadcast ds_read_b128
            const v2f hlo = {h4.x, h4.y};
            const v2f hhi = {h4.z, h4.w};
            a0 = __builtin_elementwise_fma(wa[2 * k4],     hlo, a0);
            b0 = __builtin_elementwise_fma(wb[2 * k4],     hlo, b0);
            a1 = __builtin_elementwise_fma(wa[2 * k4 + 1], hhi, a1);
            b1 = __builtin_elementwise_fma(wb[2 * k4 + 1], hhi, b1);
        }
        const float z_a = fmaf(xt, wx_a, bi_a) + (a0.x + a0.y) + (a1.x + a1.y);
        const float z_b = fmaf(xt, wx_b, bi_b) + (b0.x + b0.y) + (b1.x + b1.y);

        const float act_a = fast_sigmoid(z_a);                       // i or f
        const float act_b = fmaf(scl_o, fast_sigmoid(scl_i * z_b), off_o); // g or o

        if (wave == 1) gbuf[lane] = v2f{act_a, act_b};   // {f, o}
        __syncthreads();
        if (wave == 0) {
            const v2f fo = gbuf[lc];                     // {f, o}
            c = fmaf(fo.x, c, act_a * act_b);            // f*c + i*g
            h = fo.y * fast_tanh(c);
            if (lane < HID) hbuf[lane] = h;
        }
        __syncthreads();
    }

    // out[b] = h_T . Wd + bd  (wave 0 has h in registers)
    if (wave == 0) {
        float v = (lane < HID) ? h * Wd[lane] : 0.0f;
        #pragma unroll
        for (int off = 32; off > 0; off >>= 1) v += __shfl_down(v, off);
        if (lane == 0) out[b] = v + bd[0];
    }
}

extern "C" void kernel_launch(void* const* d_in, const int* in_sizes, int n_in,
                              void* d_out, int out_size, void* d_ws, size_t ws_size,
                              hipStream_t stream) {
    const float* x    = (const float*)d_in[0];  // [1024, 2048, 1]
    const float* Wx   = (const float*)d_in[1];  // [1, 200]
    const float* Wh   = (const float*)d_in[2];  // [50, 200]
    const float* bias = (const float*)d_in[3];  // [200]
    const float* Wd   = (const float*)d_in[4];  // [50, 1]
    const float* bd   = (const float*)d_in[5];  // [1]
    float* out = (float*)d_out;                 // [1024, 1]

    lstm_2wave_kernel<<<dim3(NBATCH), dim3(128), 0, stream>>>(
        x, Wx, Wh, bias, Wd, bd, out);
}

// Round 4
// 1195.946 us; speedup vs baseline: 1.0552x; 1.0552x over previous
//
#include <hip/hip_runtime.h>
#include <hip/hip_bf16.h>

#define HID 50
#define FOURH 200
#define TSTEPS 2048
#define NBATCH 1024

typedef float v2f __attribute__((ext_vector_type(2)));

__device__ __forceinline__ float fast_sigmoid(float x) {
    // 1/(1+e^-x); safe at both tails
    return 1.0f / (1.0f + __expf(-x));
}
__device__ __forceinline__ float fast_tanh(float x) {
    // tanh(x) = 1 - 2/(e^{2x}+1); saturates to +/-1 without NaN for large |x|
    return 1.0f - 2.0f / (__expf(2.0f * x) + 1.0f);
}
__device__ __forceinline__ float rl(float v, int lane) {
    // broadcast lane's value to all lanes via SGPR (v_readlane_b32)
    return __uint_as_float(__builtin_amdgcn_readlane(__float_as_uint(v), lane));
}

// One wave per batch element; lane l owns hidden unit min(l,49): all 4 gate
// columns of Wh for that unit live in registers (100 v2f -> v_pk_fma_f32).
// The recurrence is REGISTER-ONLY: h is broadcast lane->all via v_readlane
// (SGPR pairs feed the pk_fma stream), so the per-step LDS round-trip and
// barrier of R2 are gone. Only in-loop LDS access is xs[t], off the critical
// path (x contribution added after the dot). Lanes 50..63 compute a finite
// duplicate of unit 49 and are never read.
__global__ __launch_bounds__(64, 1)
void lstm_rl_kernel(const float* __restrict__ x,
                    const float* __restrict__ Wx,
                    const float* __restrict__ Wh,
                    const float* __restrict__ bias,
                    const float* __restrict__ Wd,
                    const float* __restrict__ bd,
                    float* __restrict__ out) {
    const int b    = blockIdx.x;
    const int lane = threadIdx.x;
    const int lc   = (lane < HID) ? lane : (HID - 1);

    __shared__ __align__(16) float xs[TSTEPS];   // 8 KB input sequence

    // Stage x (coalesced float4 loads).
    const float4* xb4 = (const float4*)(x + (size_t)b * TSTEPS);
    float4* xs4 = (float4*)xs;
    #pragma unroll
    for (int i = lane; i < TSTEPS / 4; i += 64) xs4[i] = xb4[i];

    // Per-unit weights for all 4 gates, paired along k for v_pk_fma_f32.
    v2f wi[25], wf[25], wg[25], wo[25];
    #pragma unroll
    for (int k2 = 0; k2 < 25; ++k2) {
        const float* r0 = Wh + (2 * k2) * FOURH;
        const float* r1 = Wh + (2 * k2 + 1) * FOURH;
        wi[k2] = v2f{r0[lc],           r1[lc]};
        wf[k2] = v2f{r0[HID + lc],     r1[HID + lc]};
        wg[k2] = v2f{r0[2 * HID + lc], r1[2 * HID + lc]};
        wo[k2] = v2f{r0[3 * HID + lc], r1[3 * HID + lc]};
    }
    const float wx_i = Wx[lc],           b_i = bias[lc];
    const float wx_f = Wx[HID + lc],     b_f = bias[HID + lc];
    const float wx_g = Wx[2 * HID + lc], b_g = bias[2 * HID + lc];
    const float wx_o = Wx[3 * HID + lc], b_o = bias[3 * HID + lc];

    float c = 0.0f;
    float h = 0.0f;
    __syncthreads();   // one-time: xs staging visible to all lanes

    for (int t = 0; t < TSTEPS; ++t) {
        const float xt = xs[t];   // LDS read; latency hidden under the dot
        v2f ai = {0.0f, 0.0f}, af = {0.0f, 0.0f};
        v2f ag = {0.0f, 0.0f}, ao = {0.0f, 0.0f};
        #pragma unroll
        for (int k2 = 0; k2 < 25; ++k2) {
            // h_{2k2}, h_{2k2+1} broadcast from lanes via readlane (SGPRs).
            const v2f hh = {rl(h, 2 * k2), rl(h, 2 * k2 + 1)};
            ai = __builtin_elementwise_fma(wi[k2], hh, ai);
            af = __builtin_elementwise_fma(wf[k2], hh, af);
            ag = __builtin_elementwise_fma(wg[k2], hh, ag);
            ao = __builtin_elementwise_fma(wo[k2], hh, ao);
        }
        const float zi = fmaf(xt, wx_i, b_i) + (ai.x + ai.y);
        const float zf = fmaf(xt, wx_f, b_f) + (af.x + af.y);
        const float zg = fmaf(xt, wx_g, b_g) + (ag.x + ag.y);
        const float zo = fmaf(xt, wx_o, b_o) + (ao.x + ao.y);

        const float ig = fast_sigmoid(zi);
        const float fg = fast_sigmoid(zf);
        const float gg = fast_tanh(zg);
        const float og = fast_sigmoid(zo);
        c = fmaf(fg, c, ig * gg);
        h = og * fast_tanh(c);
    }

    // out[b] = h_T . Wd + bd
    float v = (lane < HID) ? h * Wd[lane] : 0.0f;
    #pragma unroll
    for (int off = 32; off > 0; off >>= 1) v += __shfl_down(v, off);
    if (lane == 0) out[b] = v + bd[0];
}

extern "C" void kernel_launch(void* const* d_in, const int* in_sizes, int n_in,
                              void* d_out, int out_size, void* d_ws, size_t ws_size,
                              hipStream_t stream) {
    const float* x    = (const float*)d_in[0];  // [1024, 2048, 1]
    const float* Wx   = (const float*)d_in[1];  // [1, 200]
    const float* Wh   = (const float*)d_in[2];  // [50, 200]
    const float* bias = (const float*)d_in[3];  // [200]
    const float* Wd   = (const float*)d_in[4];  // [50, 1]
    const float* bd   = (const float*)d_in[5];  // [1]
    float* out = (float*)d_out;                 // [1024, 1]

    lstm_rl_kernel<<<dim3(NBATCH), dim3(64), 0, stream>>>(
        x, Wx, Wh, bias, Wd, bd, out);
}

// Round 5
// 872.832 us; speedup vs baseline: 1.4458x; 1.3702x over previous
//
#include <hip/hip_runtime.h>
#include <hip/hip_bf16.h>

#define HID 50
#define FOURH 200
#define TSTEPS 2048
#define NBATCH 1024

typedef float v2f __attribute__((ext_vector_type(2)));
typedef float v4f __attribute__((ext_vector_type(4)));

#define LOG2E 1.44269504f

__device__ __forceinline__ float frcp(float x)  { return __builtin_amdgcn_rcpf(x); }
__device__ __forceinline__ float fexp2(float x) { return __builtin_amdgcn_exp2f(x); }

// sigmoid(x) = 1/(1+2^(-x*log2e)) : 1 v_exp + 1 v_rcp, NaN-free at both tails
__device__ __forceinline__ float fast_sigmoid(float x) {
    return frcp(1.0f + fexp2(-LOG2E * x));
}
// tanh(x) = 1 - 2/(2^(2x*log2e)+1) : saturates to +/-1, NaN-free
__device__ __forceinline__ float fast_tanh(float x) {
    return 1.0f - 2.0f * frcp(fexp2((2.0f * LOG2E) * x) + 1.0f);
}

// One wave per batch element (1024 waves = 1/SIMD, structural). Lane l owns
// hidden unit min(l,49): all 4 gate columns in VGPRs (104 v2f -> v_pk_fma_f32,
// 8 independent chains). h broadcast via LDS: ds_write + 13x ds_read_b128,
// NO barrier (single wave: lockstep issue + in-order DS pipe; compiler's
// lgkmcnt handles the data dependency through hbuf aliasing). Activations use
// raw v_rcp/v_exp (no IEEE-div expansion). x[t+1] prefetched into a register.
__global__ __launch_bounds__(64, 1)
void lstm_fast_kernel(const float* __restrict__ x,
                      const float* __restrict__ Wx,
                      const float* __restrict__ Wh,
                      const float* __restrict__ bias,
                      const float* __restrict__ Wd,
                      const float* __restrict__ bd,
                      float* __restrict__ out) {
    const int b    = blockIdx.x;
    const int lane = threadIdx.x;
    const int lc   = (lane < HID) ? lane : (HID - 1);

    __shared__ __align__(16) float xs[TSTEPS + 4];
    __shared__ __align__(16) float hbuf[64];   // h state; slots 50..63 scratch

    // Stage x (coalesced float4 loads).
    const float4* xb4 = (const float4*)(x + (size_t)b * TSTEPS);
    float4* xs4 = (float4*)xs;
    #pragma unroll
    for (int i = lane; i < TSTEPS / 4; i += 64) xs4[i] = xb4[i];
    if (lane == 0) xs[TSTEPS] = 0.0f;          // prefetch pad
    hbuf[lane] = 0.0f;

    // Per-unit weights for all 4 gates, paired along k (pad k=50,51 with 0).
    v2f wi[26], wf[26], wg[26], wo[26];
    #pragma unroll
    for (int k2 = 0; k2 < 25; ++k2) {
        const float* r0 = Wh + (2 * k2) * FOURH;
        const float* r1 = Wh + (2 * k2 + 1) * FOURH;
        wi[k2] = v2f{r0[lc],           r1[lc]};
        wf[k2] = v2f{r0[HID + lc],     r1[HID + lc]};
        wg[k2] = v2f{r0[2 * HID + lc], r1[2 * HID + lc]};
        wo[k2] = v2f{r0[3 * HID + lc], r1[3 * HID + lc]};
    }
    wi[25] = v2f{0.0f, 0.0f}; wf[25] = v2f{0.0f, 0.0f};
    wg[25] = v2f{0.0f, 0.0f}; wo[25] = v2f{0.0f, 0.0f};
    const float wx_i = Wx[lc],           b_i = bias[lc];
    const float wx_f = Wx[HID + lc],     b_f = bias[HID + lc];
    const float wx_g = Wx[2 * HID + lc], b_g = bias[2 * HID + lc];
    const float wx_o = Wx[3 * HID + lc], b_o = bias[3 * HID + lc];

    float c = 0.0f;
    float h = 0.0f;
    __syncthreads();   // one-time: staging visible (cheap, outside loop)

    const v4f* h4p = (const v4f*)hbuf;
    float xt = xs[0];

    for (int t = 0; t < TSTEPS; ++t) {
        const float xt_next = xs[t + 1];   // off the critical path
        // 8 independent pk-fma chains (lo/hi per gate).
        v2f ai0 = {0.f, 0.f}, ai1 = {0.f, 0.f};
        v2f af0 = {0.f, 0.f}, af1 = {0.f, 0.f};
        v2f ag0 = {0.f, 0.f}, ag1 = {0.f, 0.f};
        v2f ao0 = {0.f, 0.f}, ao1 = {0.f, 0.f};
        #pragma unroll
        for (int k4 = 0; k4 < 13; ++k4) {
            const v4f h4 = h4p[k4];        // broadcast ds_read_b128
            const v2f hlo = {h4.x, h4.y};
            const v2f hhi = {h4.z, h4.w};
            ai0 = __builtin_elementwise_fma(wi[2 * k4],     hlo, ai0);
            af0 = __builtin_elementwise_fma(wf[2 * k4],     hlo, af0);
            ag0 = __builtin_elementwise_fma(wg[2 * k4],     hlo, ag0);
            ao0 = __builtin_elementwise_fma(wo[2 * k4],     hlo, ao0);
            ai1 = __builtin_elementwise_fma(wi[2 * k4 + 1], hhi, ai1);
            af1 = __builtin_elementwise_fma(wf[2 * k4 + 1], hhi, af1);
            ag1 = __builtin_elementwise_fma(wg[2 * k4 + 1], hhi, ag1);
            ao1 = __builtin_elementwise_fma(wo[2 * k4 + 1], hhi, ao1);
        }
        const v2f si = ai0 + ai1, sf = af0 + af1;
        const v2f sg = ag0 + ag1, so = ao0 + ao1;
        const float zi = fmaf(xt, wx_i, b_i) + (si.x + si.y);
        const float zf = fmaf(xt, wx_f, b_f) + (sf.x + sf.y);
        const float zg = fmaf(xt, wx_g, b_g) + (sg.x + sg.y);
        const float zo = fmaf(xt, wx_o, b_o) + (so.x + so.y);

        const float ig = fast_sigmoid(zi);
        const float fg = fast_sigmoid(zf);
        const float gg = fast_tanh(zg);
        const float og = fast_sigmoid(zo);
        c = fmaf(fg, c, ig * gg);
        h = og * fast_tanh(c);

        hbuf[lane] = h;   // ds_write; same-wave DS ordering, no barrier needed
        xt = xt_next;
    }

    // out[b] = h_T . Wd + bd
    float v = (lane < HID) ? h * Wd[lane] : 0.0f;
    #pragma unroll
    for (int off = 32; off > 0; off >>= 1) v += __shfl_down(v, off);
    if (lane == 0) out[b] = v + bd[0];
}

extern "C" void kernel_launch(void* const* d_in, const int* in_sizes, int n_in,
                              void* d_out, int out_size, void* d_ws, size_t ws_size,
                              hipStream_t stream) {
    const float* x    = (const float*)d_in[0];  // [1024, 2048, 1]
    const float* Wx   = (const float*)d_in[1];  // [1, 200]
    const float* Wh   = (const float*)d_in[2];  // [50, 200]
    const float* bias = (const float*)d_in[3];  // [200]
    const float* Wd   = (const float*)d_in[4];  // [50, 1]
    const float* bd   = (const float*)d_in[5];  // [1]
    float* out = (float*)d_out;                 // [1024, 1]

    lstm_fast_kernel<<<dim3(NBATCH), dim3(64), 0, stream>>>(
        x, Wx, Wh, bias, Wd, bd, out);
}

// Round 6
// 783.972 us; speedup vs baseline: 1.6097x; 1.1133x over previous
//
#include <hip/hip_runtime.h>
#include <hip/hip_bf16.h>

#define HID 50
#define FOURH 200
#define TSTEPS 2048
#define NBATCH 1024

typedef _Float16 v2h __attribute__((ext_vector_type(2)));

#define LOG2E 1.44269504f

__device__ __forceinline__ float frcp(float x)  { return __builtin_amdgcn_rcpf(x); }
__device__ __forceinline__ float fexp2(float x) { return __builtin_amdgcn_exp2f(x); }

// sigmoid(x) = 1/(1+2^(-x*log2e)) : 1 v_exp + 1 v_rcp, NaN-free at both tails
__device__ __forceinline__ float fast_sigmoid(float x) {
    return frcp(1.0f + fexp2(-LOG2E * x));
}
// tanh(x) = 1 - 2/(2^(2x*log2e)+1) : saturates to +/-1, NaN-free
__device__ __forceinline__ float fast_tanh(float x) {
    return 1.0f - 2.0f * frcp(fexp2((2.0f * LOG2E) * x) + 1.0f);
}

__device__ __forceinline__ v2h bc_v2h(unsigned int u) {
    return __builtin_bit_cast(v2h, u);
}

// One wave per batch (1024 waves = 1/SIMD). Lane l owns hidden unit min(l,49).
// Recurrent dot Wh·h runs in f16 via v_dot2_f32_f16 (fp32 accumulate): h is
// stored in LDS as f16, read back as 7x ds_read_b128 of PACKED half2 pairs
// (uint -> v2h bit_cast, no repack); Wh columns pre-packed to half2 in VGPRs.
// Everything else (x path, bias, c, tanh, output) stays fp32. No in-loop
// barrier (single wave). Lanes 50..63 write scratch LDS slots (56..77) so the
// padding halves 50..55 stay zero.
__global__ __launch_bounds__(64, 1)
void lstm_dot2_kernel(const float* __restrict__ x,
                      const float* __restrict__ Wx,
                      const float* __restrict__ Wh,
                      const float* __restrict__ bias,
                      const float* __restrict__ Wd,
                      const float* __restrict__ bd,
                      float* __restrict__ out) {
    const int b    = blockIdx.x;
    const int lane = threadIdx.x;
    const int lc   = (lane < HID) ? lane : (HID - 1);

    __shared__ __align__(16) float    xs[TSTEPS + 4];
    __shared__ __align__(16) _Float16 hbuf[80];   // [0..55] real+pad, [56..79] scratch

    // Stage x (coalesced float4 loads).
    const float4* xb4 = (const float4*)(x + (size_t)b * TSTEPS);
    float4* xs4 = (float4*)xs;
    #pragma unroll
    for (int i = lane; i < TSTEPS / 4; i += 64) xs4[i] = xb4[i];
    if (lane == 0) xs[TSTEPS] = 0.0f;
    for (int i = lane; i < 80; i += 64) hbuf[i] = (_Float16)0.0f;

    // Per-unit weights for all 4 gates, packed along k as half2 (25 pairs = k 0..49).
    v2h wi[25], wf[25], wg[25], wo[25];
    #pragma unroll
    for (int k2 = 0; k2 < 25; ++k2) {
        const float* r0 = Wh + (2 * k2) * FOURH;
        const float* r1 = Wh + (2 * k2 + 1) * FOURH;
        wi[k2] = v2h{(_Float16)r0[lc],           (_Float16)r1[lc]};
        wf[k2] = v2h{(_Float16)r0[HID + lc],     (_Float16)r1[HID + lc]};
        wg[k2] = v2h{(_Float16)r0[2 * HID + lc], (_Float16)r1[2 * HID + lc]};
        wo[k2] = v2h{(_Float16)r0[3 * HID + lc], (_Float16)r1[3 * HID + lc]};
    }
    const float wx_i = Wx[lc],           b_i = bias[lc];
    const float wx_f = Wx[HID + lc],     b_f = bias[HID + lc];
    const float wx_g = Wx[2 * HID + lc], b_g = bias[2 * HID + lc];
    const float wx_o = Wx[3 * HID + lc], b_o = bias[3 * HID + lc];

    // Branchless write slot: real units -> [0..49], dup lanes -> [64..77].
    const int widx = (lane < HID) ? lane : (lane + 14);

    float c = 0.0f;
    float h = 0.0f;
    __syncthreads();   // one-time: staging visible

    const uint4* hb4 = (const uint4*)hbuf;   // 7 x b128 = 56 halves
    float xt = xs[0];

    for (int t = 0; t < TSTEPS; ++t) {
        const float xt_next = xs[t + 1];
        // Load packed h pairs (no repack: each uint IS a half2).
        const uint4 q0 = hb4[0], q1 = hb4[1], q2 = hb4[2], q3 = hb4[3];
        const uint4 q4 = hb4[4], q5 = hb4[5], q6 = hb4[6];
        unsigned int hr[28] = {q0.x, q0.y, q0.z, q0.w, q1.x, q1.y, q1.z, q1.w,
                               q2.x, q2.y, q2.z, q2.w, q3.x, q3.y, q3.z, q3.w,
                               q4.x, q4.y, q4.z, q4.w, q5.x, q5.y, q5.z, q5.w,
                               q6.x, q6.y, q6.z, q6.w};
        // 8 independent dot2 chains (2 per gate).
        float ai0 = 0.f, ai1 = 0.f, af0 = 0.f, af1 = 0.f;
        float ag0 = 0.f, ag1 = 0.f, ao0 = 0.f, ao1 = 0.f;
        #pragma unroll
        for (int j = 0; j < 12; ++j) {
            const v2h hp0 = bc_v2h(hr[2 * j]);
            const v2h hp1 = bc_v2h(hr[2 * j + 1]);
            ai0 = __builtin_amdgcn_fdot2(wi[2 * j],     hp0, ai0, false);
            af0 = __builtin_amdgcn_fdot2(wf[2 * j],     hp0, af0, false);
            ag0 = __builtin_amdgcn_fdot2(wg[2 * j],     hp0, ag0, false);
            ao0 = __builtin_amdgcn_fdot2(wo[2 * j],     hp0, ao0, false);
            ai1 = __builtin_amdgcn_fdot2(wi[2 * j + 1], hp1, ai1, false);
            af1 = __builtin_amdgcn_fdot2(wf[2 * j + 1], hp1, af1, false);
            ag1 = __builtin_amdgcn_fdot2(wg[2 * j + 1], hp1, ag1, false);
            ao1 = __builtin_amdgcn_fdot2(wo[2 * j + 1], hp1, ao1, false);
        }
        {   // pair 24 (h48,h49)
            const v2h hp = bc_v2h(hr[24]);
            ai0 = __builtin_amdgcn_fdot2(wi[24], hp, ai0, false);
            af0 = __builtin_amdgcn_fdot2(wf[24], hp, af0, false);
            ag0 = __builtin_amdgcn_fdot2(wg[24], hp, ag0, false);
            ao0 = __builtin_amdgcn_fdot2(wo[24], hp, ao0, false);
        }
        const float zi = fmaf(xt, wx_i, b_i) + (ai0 + ai1);
        const float zf = fmaf(xt, wx_f, b_f) + (af0 + af1);
        const float zg = fmaf(xt, wx_g, b_g) + (ag0 + ag1);
        const float zo = fmaf(xt, wx_o, b_o) + (ao0 + ao1);

        const float ig = fast_sigmoid(zi);
        const float fg = fast_sigmoid(zf);
        const float gg = fast_tanh(zg);
        const float og = fast_sigmoid(zo);
        c = fmaf(fg, c, ig * gg);
        h = og * fast_tanh(c);

        hbuf[widx] = (_Float16)h;   // ds_write_b16; same-wave DS ordering
        xt = xt_next;
    }

    // out[b] = h_T . Wd + bd  (fp32 h from registers)
    float v = (lane < HID) ? h * Wd[lane] : 0.0f;
    #pragma unroll
    for (int off = 32; off > 0; off >>= 1) v += __shfl_down(v, off);
    if (lane == 0) out[b] = v + bd[0];
}

extern "C" void kernel_launch(void* const* d_in, const int* in_sizes, int n_in,
                              void* d_out, int out_size, void* d_ws, size_t ws_size,
                              hipStream_t stream) {
    const float* x    = (const float*)d_in[0];  // [1024, 2048, 1]
    const float* Wx   = (const float*)d_in[1];  // [1, 200]
    const float* Wh   = (const float*)d_in[2];  // [50, 200]
    const float* bias = (const float*)d_in[3];  // [200]
    const float* Wd   = (const float*)d_in[4];  // [50, 1]
    const float* bd   = (const float*)d_in[5];  // [1]
    float* out = (float*)d_out;                 // [1024, 1]

    lstm_dot2_kernel<<<dim3(NBATCH), dim3(64), 0, stream>>>(
        x, Wx, Wh, bias, Wd, bd, out);
}